// Round 5
// baseline (374.797 us; speedup 1.0000x reference)
//
#include <hip/hip_runtime.h>

// NormConv2d: depthwise 3x3 correlation with L2-normalized filters, divided by
// per-patch L2 norm. x: (16,3,1024,1024) fp32, w: (3,1,3,3) fp32, zero-pad 1.
//
// Round 7: decouple stores from the load pipeline + restore TLP + kill gathers.
// Round-6 post-mortem: registerization worked (VGPR=60, WRITE_SIZE==output,
// scratch gone) but 136us > round-0's 121us -> the per-step waits are NOT
// load latency. Revised model: (1) vmcnt is FIFO, so each step's load-wait
// also drains the NT stores issued in between (store-completion tax per
// step); (2) ROWS=16 halved the block count (12/CU, occupancy 41%);
// (3) the two per-row scalar halo loads are 16B-stride gathers touching
// ~16 lines each (48 line-touches/row vs 18 needed).
// Changes:
//  - Defer ALL stores to the block epilogue: 8 output rows accumulate in
//    32 VGPRs; the K-loop's vmcnt waits see loads only.
//  - ROWS=8 (6144 blocks, 24/CU) with the proven 5-named-slot distance-2
//    register pipeline (every index compile-time constant).
//  - Halo via wave shuffle at consume time: rows are loaded as one aligned
//    dwordx4 (+ exec-masked single-lane edge loads); left/right neighbors
//    come from __shfl_up/__shfl_down (ds_bpermute, no LDS, no gathers).
// XCD swizzle: same (blockIdx & 7) == same XCD under round-robin dispatch,
// mapped to contiguous logical tiles so halo rows hit that XCD's L2.

#define HH 1024
#define WW 1024
#define CC 3
#define NN 16
#define ROWS 8
#define TILES (HH / ROWS)        // 128 tiles per plane
#define NBLK (NN * CC * TILES)   // 6144 blocks (24 per CU, uniform)

typedef float f32x4 __attribute__((ext_vector_type(4)));

// Issue the loads for one input row. Raw slot layout: {c0,c1,c2,c3, eL, eR}
// where c* is the aligned dwordx4 and eL/eR are only valid on lanes 0/63.
// No shuffles here -> nothing forces a vmcnt wait at issue time.
__device__ __forceinline__ void load_row_raw(const float* __restrict__ base, int y,
                                             int x0, int lane, float* __restrict__ s)
{
    if ((unsigned)y >= (unsigned)HH) {   // zero-pad top/bottom (block-uniform)
        s[0] = s[1] = s[2] = s[3] = s[4] = s[5] = 0.f;
    } else {
        const float* p = base + y * WW;
        const float4 c4 = *(const float4*)(p + x0);       // 16B-aligned
        s[0] = c4.x; s[1] = c4.y; s[2] = c4.z; s[3] = c4.w;
        float eL = 0.f, eR = 0.f;
        if (lane == 0 && x0 > 0)       eL = p[x0 - 1];    // wave-left edge
        if (lane == 63 && x0 + 4 < WW) eR = p[x0 + 4];    // wave-right edge
        s[4] = eL; s[5] = eR;
    }
}

// Convert raw slot -> 6-wide window {left, c0..c3, right} via wave shuffles.
// Called once per row, two steps after its load was issued (distance-2).
__device__ __forceinline__ void convert6(int lane, float* __restrict__ s)
{
    float l = __shfl_up(s[3], 1);        // lane L-1's c3 == px[x0-1]
    float r = __shfl_down(s[0], 1);      // lane L+1's c0 == px[x0+4]
    l = (lane == 0)  ? s[4] : l;
    r = (lane == 63) ? s[5] : r;
    const float c0 = s[0], c1 = s[1], c2 = s[2], c3 = s[3];
    s[0] = l; s[1] = c0; s[2] = c1; s[3] = c2; s[4] = c3; s[5] = r;
}

__device__ __forceinline__ f32x4 compute_row(
    const float* __restrict__ r0, const float* __restrict__ r1,
    const float* __restrict__ r2, const float* __restrict__ wn)
{
    // Per-column sum of squares, shared by the 3 windows that touch it.
    float colsq[6];
#pragma unroll
    for (int t = 0; t < 6; ++t)
        colsq[t] = r0[t] * r0[t] + r1[t] * r1[t] + r2[t] * r2[t];

    f32x4 o;
#pragma unroll
    for (int j = 0; j < 4; ++j) {
        float num = 0.f;
#pragma unroll
        for (int k = 0; k < 3; ++k)
            num += r0[j + k] * wn[k] + r1[j + k] * wn[3 + k] + r2[j + k] * wn[6 + k];
        const float sq = colsq[j] + colsq[j + 1] + colsq[j + 2];
        o[j] = num * rsqrtf(sq);
    }
    return o;
}

__global__ __launch_bounds__(256, 4) void normconv_kernel(
    const float* __restrict__ x, const float* __restrict__ w, float* __restrict__ out)
{
    // XCD-aware swizzle: logical tile L from physical block id b such that
    // blocks with equal (b & 7) cover a contiguous range of L.
    const int b     = blockIdx.x;
    const int L     = (b & 7) * (NBLK / 8) + (b >> 3);
    const int tile  = L & (TILES - 1);
    const int plane = L >> 7;            // L / TILES
    const int c     = plane % CC;

    // Normalized weights — block-uniform, scalarized by the compiler
    float wn[9];
    float s = 0.f;
#pragma unroll
    for (int i = 0; i < 9; ++i) { float wi = w[c * 9 + i]; wn[i] = wi; s += wi * wi; }
    const float winv = rsqrtf(s);
#pragma unroll
    for (int i = 0; i < 9; ++i) wn[i] *= winv;

    const int lane = threadIdx.x & 63;
    const int x0 = threadIdx.x << 2;                 // 4 outputs per thread
    const int y0 = tile * ROWS;
    const float* base  = x   + (size_t)plane * (HH * WW);
    float*       obase = out + (size_t)plane * (HH * WW);

    // Five NAMED slots, period-5 rotation: slot((r+1)%5) holds input row y0+r.
    // All indices compile-time constants -> everything lives in VGPRs.
    float sA[6], sB[6], sC[6], sD[6], sE[6];
    load_row_raw(base, y0 - 1, x0, lane, sA);        // 4 loads in flight
    load_row_raw(base, y0 + 0, x0, lane, sB);
    load_row_raw(base, y0 + 1, x0, lane, sC);
    load_row_raw(base, y0 + 2, x0, lane, sD);
    convert6(lane, sA);                              // rows -1,0 ready for step 0
    convert6(lane, sB);

    // Step I: issue load of row I+3 (consumed at step I+2), convert row I+1
    // (loaded at step I-2), compute output row I into a register.
    f32x4 o0, o1, o2, o3, o4, o5, o6, o7;
#define STEP(I, R0, R1, R2, PF, CV, OUT)                                       \
    do {                                                                       \
        if ((I) + 3 <= ROWS) load_row_raw(base, y0 + (I) + 3, x0, lane, PF);   \
        convert6(lane, CV);                                                    \
        OUT = compute_row(R0, R1, R2, wn);                                     \
    } while (0)

    STEP(0, sA, sB, sC, sE, sC, o0);
    STEP(1, sB, sC, sD, sA, sD, o1);
    STEP(2, sC, sD, sE, sB, sE, o2);
    STEP(3, sD, sE, sA, sC, sA, o3);
    STEP(4, sE, sA, sB, sD, sB, o4);
    STEP(5, sA, sB, sC, sE, sC, o5);
    STEP(6, sB, sC, sD, sA, sD, o6);   // PF guard false (9 > 8): no load
    STEP(7, sC, sD, sE, sA, sE, o7);   // PF guard false: no load
#undef STEP

    // Epilogue: burst the 8 output rows. Stores never block the loop's vmcnt.
    float* orow = obase + (size_t)y0 * WW + x0;
    __builtin_nontemporal_store(o0, (f32x4*)(orow + 0 * WW));
    __builtin_nontemporal_store(o1, (f32x4*)(orow + 1 * WW));
    __builtin_nontemporal_store(o2, (f32x4*)(orow + 2 * WW));
    __builtin_nontemporal_store(o3, (f32x4*)(orow + 3 * WW));
    __builtin_nontemporal_store(o4, (f32x4*)(orow + 4 * WW));
    __builtin_nontemporal_store(o5, (f32x4*)(orow + 5 * WW));
    __builtin_nontemporal_store(o6, (f32x4*)(orow + 6 * WW));
    __builtin_nontemporal_store(o7, (f32x4*)(orow + 7 * WW));
}

extern "C" void kernel_launch(void* const* d_in, const int* in_sizes, int n_in,
                              void* d_out, int out_size, void* d_ws, size_t ws_size,
                              hipStream_t stream) {
    const float* x = (const float*)d_in[0];
    const float* w = (const float*)d_in[1];
    float* out = (float*)d_out;

    normconv_kernel<<<NBLK, 256, 0, stream>>>(x, w, out);
}

// Round 7
// 337.092 us; speedup vs baseline: 1.1119x; 1.1119x over previous
//
#include <hip/hip_runtime.h>

// NormConv2d: depthwise 3x3 correlation with L2-normalized filters, divided by
// per-patch L2 norm. x: (16,3,1024,1024) fp32, w: (3,1,3,3) fp32, zero-pad 1.
//
// Round 9 = Round 8 resubmitted (bench infra failed twice; no kernel signal).
// Round 8: async LDS staging via __builtin_amdgcn_global_load_lds.
// History: every register-resident software pipeline (rounds 3-7) either
// spilled to scratch (R5: WRITE 478MB; R7: WRITE 368MB, +172MB spill traffic)
// or was silently collapsed by the compiler sinking loads to their uses
// (R6: VGPR=60, exact write size, but 136us == no pipeline effect).
// Counters show FETCH+WRITE far below the HBM wall and VALUBusy ~25% ->
// latency-bound, and source-level prefetch via plain loads is un-pinnable.
// Mechanism change: global_load_lds is an async DMA the compiler cannot sink
// and that consumes ZERO VGPRs in flight.
// Per block (256 thr, 8 output rows of one plane):
//   - issue 10 row DMAs (8 rows + 2 halo rows, 4KB each) back-to-back:
//     ~40KB in flight per block, no register pressure;
//   - out-of-range pad rows are zero-filled in LDS by ds_write (block-uniform);
//   - ONE __syncthreads (vmcnt0 drain is fine: nothing to overlap in-block;
//     cross-BLOCK overlap -- 4 resident blocks/CU, LDS-capped -- hides it);
//   - compute 8 rows from LDS: 1 ds_read_b128 + 2 halo b32 per row,
//     3-slot named rotation (all indices compile-time), inline NT stores.
// XCD swizzle: same (blockIdx & 7) == same XCD under round-robin dispatch,
// mapped to contiguous logical tiles so halo rows hit that XCD's L2.

#define HH 1024
#define WW 1024
#define CC 3
#define NN 16
#define ROWS 8
#define LROWS (ROWS + 2)         // 10 staged rows = 40KB LDS
#define TILES (HH / ROWS)        // 128 tiles per plane
#define NBLK (NN * CC * TILES)   // 6144 blocks (24 per CU, uniform)

typedef float f32x4 __attribute__((ext_vector_type(4)));

// Read the 6-wide window {x0-1 .. x0+4} of one staged LDS row.
__device__ __forceinline__ void read6(const float* __restrict__ lrow, int x0,
                                      float* __restrict__ s)
{
    const f32x4 c4 = *(const f32x4*)(lrow + x0);          // ds_read_b128
    s[1] = c4.x; s[2] = c4.y; s[3] = c4.z; s[4] = c4.w;
    s[0] = (x0 > 0)       ? lrow[x0 - 1] : 0.f;           // image-edge pad
    s[5] = (x0 + 4 < WW)  ? lrow[x0 + 4] : 0.f;
}

__device__ __forceinline__ f32x4 compute_row(
    const float* __restrict__ r0, const float* __restrict__ r1,
    const float* __restrict__ r2, const float* __restrict__ wn)
{
    // Per-column sum of squares, shared by the 3 windows that touch it.
    float colsq[6];
#pragma unroll
    for (int t = 0; t < 6; ++t)
        colsq[t] = r0[t] * r0[t] + r1[t] * r1[t] + r2[t] * r2[t];

    f32x4 o;
#pragma unroll
    for (int j = 0; j < 4; ++j) {
        float num = 0.f;
#pragma unroll
        for (int k = 0; k < 3; ++k)
            num += r0[j + k] * wn[k] + r1[j + k] * wn[3 + k] + r2[j + k] * wn[6 + k];
        const float sq = colsq[j] + colsq[j + 1] + colsq[j + 2];
        o[j] = num * rsqrtf(sq);
    }
    return o;
}

__global__ __launch_bounds__(256, 4) void normconv_kernel(
    const float* __restrict__ x, const float* __restrict__ w, float* __restrict__ out)
{
    __shared__ float lds[LROWS][WW];                 // 40KB -> 4 blocks/CU

    // XCD-aware swizzle: logical tile L from physical block id b such that
    // blocks with equal (b & 7) cover a contiguous range of L.
    const int b     = blockIdx.x;
    const int L     = (b & 7) * (NBLK / 8) + (b >> 3);
    const int tile  = L & (TILES - 1);
    const int plane = L >> 7;            // L / TILES
    const int c     = plane % CC;

    const int tid  = threadIdx.x;
    const int x0   = tid << 2;                       // 4 px per thread
    const int y0   = tile * ROWS;
    const float* base  = x   + (size_t)plane * (HH * WW);
    float*       obase = out + (size_t)plane * (HH * WW);

    // ---- async stage: 10 rows, one global_load_lds (16B/lane) per wave/row.
    // LDS dest is wave-uniform base + lane*16: wave w covers floats
    // [w*256, w*256+255] of the row; lane l's gsrc = row cols 256w+4l..+3.
    const int woff = (tid & ~63) << 2;               // wave*256 floats
#pragma unroll
    for (int r = 0; r < LROWS; ++r) {
        const int y = y0 - 1 + r;
        if ((unsigned)y < (unsigned)HH) {            // block-uniform branch
            const float* g = base + (size_t)y * WW + x0;
            __builtin_amdgcn_global_load_lds(
                (const __attribute__((address_space(1))) unsigned int*)g,
                (__attribute__((address_space(3))) unsigned int*)(&lds[r][woff]),
                16, 0, 0);
        } else {
            *(f32x4*)&lds[r][x0] = (f32x4)0.f;       // zero-pad row (ds_write)
        }
    }

    // Normalized weights — block-uniform, computed while DMAs are in flight.
    float wn[9];
    float s = 0.f;
#pragma unroll
    for (int i = 0; i < 9; ++i) { float wi = w[c * 9 + i]; wn[i] = wi; s += wi * wi; }
    const float winv = rsqrtf(s);
#pragma unroll
    for (int i = 0; i < 9; ++i) wn[i] *= winv;

    __syncthreads();                                 // drain DMA + LDS visible

    // ---- compute: 3 named slots, period-3 rotation, all static indices.
    float rA[6], rB[6], rC[6];
    read6(lds[0], x0, rA);                           // row y0-1
    read6(lds[1], x0, rB);                           // row y0

#define STEP(I, R0, R1, R2)                                                    \
    do {                                                                       \
        read6(lds[(I) + 2], x0, R2);                 /* row y0+I+1 */          \
        const f32x4 o = compute_row(R0, R1, R2, wn);                           \
        __builtin_nontemporal_store(o, (f32x4*)(obase + (size_t)(y0 + (I)) * WW + x0)); \
    } while (0)

    STEP(0, rA, rB, rC);
    STEP(1, rB, rC, rA);
    STEP(2, rC, rA, rB);
    STEP(3, rA, rB, rC);
    STEP(4, rB, rC, rA);
    STEP(5, rC, rA, rB);
    STEP(6, rA, rB, rC);
    STEP(7, rB, rC, rA);
#undef STEP
}

extern "C" void kernel_launch(void* const* d_in, const int* in_sizes, int n_in,
                              void* d_out, int out_size, void* d_ws, size_t ws_size,
                              hipStream_t stream) {
    const float* x = (const float*)d_in[0];
    const float* w = (const float*)d_in[1];
    float* out = (float*)d_out;

    normconv_kernel<<<NBLK, 256, 0, stream>>>(x, w, out);
}